// Round 16
// baseline (649.964 us; speedup 1.0000x reference)
//
#include <hip/hip_runtime.h>
#include <stdint.h>
#include <math.h>

// Problem dims (fixed by setup_inputs)
#define NB  16
#define NCI 128
#define NCO 256
#define NH  64
#define NWD 64

#define Y_ELEMS  (NB*NCO*NH*NWD)     // 16,777,216

// ---- workspace layout (proven ws_size >= 199,299,072) ----
#define NMAX_OFF 0                               // 256 co x 8 buckets x u64 = 16384
#define CS_OFF   16384                           // 4 x 256 x i32 = 4096
#define NBUF_OFF 23552                           // 256 x f64 = 2048
#define YD_OFF   32768                           // f64 y, (b,h,w,c) layout
#define YD_BYTES ((size_t)Y_ELEMS*8)             // 134,217,728
#define XD_OFF   (YD_OFF + YD_BYTES)             // 134,250,496
#define XD_STRIDE 7168                           // 3 digits x 2304 = 6912, padded
#define XD_BYTES ((size_t)16*4*68*XD_STRIDE)     // 31,195,136
#define WD_OFF   (XD_OFF + XD_BYTES)             // 165,445,632
#define WD_BYTES ((size_t)4*4*25*8192)           // 3,276,800 (planes p=j-1, j=1..4)
#define WS_NEED  (WD_OFF + WD_BYTES)             // 168,722,432

struct Keys { uint32_t a[8]; uint32_t b[8]; };

typedef int v4i  __attribute__((ext_vector_type(4)));
typedef int v16i __attribute__((ext_vector_type(16)));

typedef __attribute__((address_space(1))) const void* gas_t;
typedef __attribute__((address_space(3))) void*       las_t;

// JAX threefry2x32 (20 rounds), bit-exact (verified rounds 2-15).
__host__ __device__ inline void threefry2x32(uint32_t k0, uint32_t k1,
                                             uint32_t x0, uint32_t x1,
                                             uint32_t* o0, uint32_t* o1)
{
  uint32_t ks2 = k0 ^ k1 ^ 0x1BD11BDAu;
  x0 += k0; x1 += k1;
#define TF_R(r) { x0 += x1; x1 = (x1 << (r)) | (x1 >> (32 - (r))); x1 ^= x0; }
  TF_R(13) TF_R(15) TF_R(26) TF_R(6)
  x0 += k1;  x1 += ks2 + 1u;
  TF_R(17) TF_R(29) TF_R(16) TF_R(24)
  x0 += ks2; x1 += k0 + 2u;
  TF_R(13) TF_R(15) TF_R(26) TF_R(6)
  x0 += k0;  x1 += k1 + 3u;
  TF_R(17) TF_R(29) TF_R(16) TF_R(24)
  x0 += k1;  x1 += ks2 + 4u;
  TF_R(13) TF_R(15) TF_R(26) TF_R(6)
  x0 += ks2; x1 += k0 + 5u;
#undef TF_R
  *o0 = x0; *o1 = x1;
}

__device__ inline unsigned long long dkey(double d)
{
  unsigned long long b = (unsigned long long)__double_as_longlong(d);
  return (b & 0x8000000000000000ULL) ? ~b : (b | 0x8000000000000000ULL);
}

// ---------------- digit extraction for x: 3 x 8-bit digits MINUS 128 (signed-safe) ----
// Block (0,0,0) also zero-inits nmax + cs (stream order: before wdigit's atomics).
__global__ __launch_bounds__(256) void xdigit_kernel(const float* __restrict__ x,
                                                     signed char* __restrict__ xd,
                                                     unsigned long long* __restrict__ nmax,
                                                     int* __restrict__ cs)
{
  __shared__ __align__(16) signed char l[6912];
  const int row = blockIdx.x;  // padded row 0..67
  const int g   = blockIdx.y;  // ci group 0..3
  const int b   = blockIdx.z;

  if (row == 0 && g == 0 && b == 0) {
    #pragma unroll
    for (int i = 0; i < 8; ++i) nmax[i * 256 + threadIdx.x] = 0ull;
    #pragma unroll
    for (int p = 0; p < 4; ++p) cs[p * 256 + threadIdx.x] = 0;
  }

  for (int o = threadIdx.x; o < 2304; o += 256) {
    int cl = o / 72, col = o - (o / 72) * 72;
    int r = row - 2, cc = col - 2;
    float v = 0.f;
    if ((unsigned)r < 64u && (unsigned)cc < 64u)
      v = x[(((size_t)b * 128 + g * 32 + cl) * 64 + r) * 64 + cc];
    unsigned long long X = (unsigned long long)((double)v * 1099511627776.0); // 2^40 exact
    const int p = col * 32 + cl;
    l[p]        = (signed char)((int)((X >> 16) & 255u) - 128);
    l[2304 + p] = (signed char)((int)((X >> 24) & 255u) - 128);
    l[4608 + p] = (signed char)((int)((X >> 32) & 255u) - 128);
  }
  __syncthreads();
  uint4* dst = (uint4*)(xd + ((size_t)(b * 4 + g) * 68 + row) * XD_STRIDE);
  const uint4* src = (const uint4*)l;
  for (int o = threadIdx.x; o < 432; o += 256) dst[o] = src[o];
}

// ---------------- balanced 8-bit digit extraction for w: scale 2^36, store j=1..4 ----
__global__ __launch_bounds__(256) void wdigit_kernel(const float* __restrict__ W,
                                                     signed char* __restrict__ wd,
                                                     int* __restrict__ cs)
{
  const int g = blockIdx.x, tap = blockIdx.y, co = threadIdx.x;
  __attribute__((aligned(16))) signed char db[5][32];
  for (int c = 0; c < 32; ++c) {
    float w = W[((size_t)co * 128 + g * 32 + c) * 25 + tap];
    long long q = __double2ll_rn((double)w * 68719476736.0); // 2^36
    #pragma unroll
    for (int j = 0; j < 5; ++j) {
      int d = (int)(q & 255);
      if (d >= 128) d -= 256;
      q = (q - d) >> 8;
      db[j][c] = (signed char)d;
    }
  }
  #pragma unroll
  for (int p = 0; p < 4; ++p) {
    const int j = p + 1;
    size_t off = (((size_t)p * 4 + g) * 25 + tap) * 8192 + (size_t)co * 32;
    *(uint4*)(wd + off)      = *(const uint4*)(&db[j][0]);
    *(uint4*)(wd + off + 16) = *(const uint4*)(&db[j][16]);
    int s = 0;
    #pragma unroll
    for (int c = 0; c < 32; ++c) s += (int)db[j][c];
    atomicAdd(&cs[p * 256 + co], s);
  }
}

// ---------------- i8-MFMA conv -> yd f64 (b,h,w,c), fused per-co max + shift-corr ----
// BIG-TILE variant: block = 64px x 128co (grid 2048). Wave = 32px x 64co = 2 co-tiles.
// Per kw slot: 3 shared A ds_reads + 8 B-loads feed an 18-MFMA burst (2x r15's 9).
// A-stage DMA traffic and barrier count halve globally. acc[2][4] = 128 AGPR.
__global__ __launch_bounds__(256, 2) void ozconv_kernel(const signed char* __restrict__ xd,
                                                        const signed char* __restrict__ wd,
                                                        const int* __restrict__ cs,
                                                        double* __restrict__ yd,
                                                        unsigned long long* __restrict__ nmax)
{
  __shared__ __align__(16) signed char A[2 * XD_STRIDE];

  // XCD-contiguous swizzle over 2048 blocks (256 per XCD)
  const int sid = (blockIdx.x & 7) * 256 + (blockIdx.x >> 3);
  const int cog = sid >> 10;          // 0..1
  const int b   = (sid >> 6) & 15;
  const int h0  = sid & 63;

  const int tid  = threadIdx.x;
  const int lane = tid & 63, wv = tid >> 6;
  const int wm = wv & 1, wn = wv >> 1;
  const int l31 = lane & 31, kg = lane >> 5;
  const int co0 = cog * 128;
  const int b4  = b * 4;
  const int colbase = 32 * wm + l31;

  v16i acc[2][4] = {};

  auto stage = [&](int t, int bs) {
    int g = t / 5, kh = t - 5 * (t / 5);
    const signed char* src = xd + ((size_t)(b4 + g) * 68 + (h0 + kh)) * XD_STRIDE + lane * 16;
    signed char* dst = &A[bs * XD_STRIDE];
    for (int c = wv; c < 7; c += 4)
      __builtin_amdgcn_global_load_lds((gas_t)(const void*)(src + c * 1024),
                                       (las_t)(void*)(dst + c * 1024), 16, 0, 0);
  };

  stage(0, 0);
  asm volatile("s_waitcnt vmcnt(0)" ::: "memory");
  __syncthreads();

  // two co-tiles per wave: co_ct = co0 + wn*64 + ct*32 + l31
  size_t coff[2];
  #pragma unroll
  for (int ct = 0; ct < 2; ++ct)
    coff[ct] = (size_t)(co0 + wn * 64 + ct * 32 + l31) * 32 + 16 * kg;

  #pragma unroll 1
  for (int t = 0; t < 20; ++t) {
    if (t < 19) stage(t + 1, (t + 1) & 1);   // DMA next row under this row's compute

    const int g = t / 5, kh = t - 5 * (t / 5);
    const signed char* Ab = &A[(t & 1) * XD_STRIDE];
    const signed char* wrow = wd + ((size_t)(g * 25 + kh * 5)) * 8192;

    #pragma unroll 1
    for (int kw = 0; kw < 5; ++kw) {
      const int aoff = (colbase + kw) * 32 + kg * 16;
      v4i a[3];
      #pragma unroll
      for (int i = 0; i < 3; ++i)
        a[i] = *(const v4i*)(Ab + i * 2304 + aoff);

      v4i bf[2][4];
      #pragma unroll
      for (int ct = 0; ct < 2; ++ct)
        #pragma unroll
        for (int p = 0; p < 4; ++p)
          bf[ct][p] = *(const v4i*)(wrow + (size_t)p * 819200 + kw * 8192 + coff[ct]);

      // 18-MFMA burst: pairs i+p>=2 for both co-tiles
      #pragma unroll
      for (int q = 0; q < 4; ++q) {
        const int p = 3 - q;
        #pragma unroll
        for (int i = 0; i < 3; ++i) {
          const int ss = i + p - 2;
          if (ss >= 0) {
            acc[0][ss] = __builtin_amdgcn_mfma_i32_32x32x32_i8(a[i], bf[0][p], acc[0][ss], 0, 0, 0);
            acc[1][ss] = __builtin_amdgcn_mfma_i32_32x32x32_i8(a[i], bf[1][p], acc[1][ss], 0, 0, 0);
          }
        }
      }
    }

    asm volatile("s_waitcnt vmcnt(0)" ::: "memory");
    __syncthreads();
  }

  // recombine both co-tiles: y = C(co) + sum_s acc_s * 2^(8s-36); fused per-co max
  const double S[4] = {0x1.0p-36, 0x1.0p-28, 0x1.0p-20, 0x1.0p-12};
  const double K0 = 0x1.0p-36;
  const double K1 = 0x1.0p-36 + 0x1.0p-28;
  const double K2 = 0x1.0p-36 + 0x1.0p-28 + 0x1.0p-20;
  const double K3 = 0x1.0p-28 + 0x1.0p-20 + 0x1.0p-12;

  #pragma unroll
  for (int ct = 0; ct < 2; ++ct) {
    const int co = co0 + wn * 64 + ct * 32 + l31;
    const double C = 128.0 * ((double)cs[co]        * K0 +
                              (double)cs[256 + co]  * K1 +
                              (double)cs[512 + co]  * K2 +
                              (double)cs[768 + co]  * K3);
    const size_t base = (((size_t)b * 64 + h0) * 64) * 256 + co;
    double lmax = -1.0e300;
    #pragma unroll
    for (int r = 0; r < 16; ++r) {
      int row = (r & 3) + 8 * (r >> 2) + 4 * kg;   // verified D-fragment row
      int w   = 32 * wm + row;
      double y = C;
      #pragma unroll
      for (int s = 0; s < 4; ++s) y = fma((double)acc[ct][s][r], S[s], y);
      yd[base + (size_t)w * 256] = y;
      lmax = fmax(lmax, y);
    }
    lmax = fmax(lmax, __shfl_xor(lmax, 32));       // kg pair shares co
    if (kg == 0)
      atomicMax(&nmax[co * 8 + (blockIdx.x & 7)], dkey(lmax));
  }
}

// ---------------- n[c] = max + 1e-4 ----------------
__global__ void n_kernel(const unsigned long long* __restrict__ nmax,
                         double* __restrict__ nbuf)
{
  int c = threadIdx.x;
  unsigned long long u = 0ull;
  #pragma unroll
  for (int i = 0; i < 8; ++i) {
    unsigned long long v = nmax[c * 8 + i];
    u = v > u ? v : u;
  }
  unsigned long long bits = (u & 0x8000000000000000ULL) ? (u ^ 0x8000000000000000ULL) : ~u;
  double m = __longlong_as_double((long long)bits);
  nbuf[c] = m + 1e-4;
}

// ---------------- fused squash + dynamics: 1 wave = 1 pixel (verified rounds 5-15) ----
__global__ __launch_bounds__(256) void dyn_kernel(const double* __restrict__ yd,
                                                  const double* __restrict__ nbuf,
                                                  float* __restrict__ out,
                                                  Keys K, double tau)
{
  const int tid  = threadIdx.x;
  const int lane = tid & 63;
  const int wv   = tid >> 6;
  const int pix  = blockIdx.x * 4 + wv;    // b*4096 + hw
  const int b    = pix >> 12;
  const int hw   = pix & 4095;
  const int c0   = lane * 4;

  double y[4], n[4];
  {
    const double* yp = yd + (size_t)pix * 256 + c0;
    #pragma unroll
    for (int q = 0; q < 4; ++q) {
      n[q] = nbuf[c0 + q];
      double yraw = yp[q];
      double yc = yraw > 0.0 ? yraw : 0.0;
      y[q] = n[q] / (1.0 + exp(-((yc - 0.4 * n[q]) * (8.0 / n[q]))));
    }
  }

  double mem[4]; float xs[4];
  #pragma unroll
  for (int q = 0; q < 4; ++q) { mem[q] = y[q]; xs[q] = 0.f; }  // exact t=0 step

  const uint32_t ebase = (uint32_t)((b * 256 + c0) * 4096 + hw);

  #pragma unroll 1
  for (int t = 1; t < 8; ++t) {
    double m[4]; bool sp[4];
    int tot = 0;
    #pragma unroll
    for (int q = 0; q < 4; ++q) {
      m[q]  = mem[q] * tau + y[q];
      sp[q] = (m[q] - n[q]) > 0.0;
      tot  += __popcll(__ballot(sp[q]));
    }

    if (tot == 0) {
      #pragma unroll
      for (int q = 0; q < 4; ++q) mem[q] = m[q];
      continue;
    }
    if (tot == 1) {
      // lone spiker wins WTA unconditionally; inhibition fires (smax=1)
      #pragma unroll
      for (int q = 0; q < 4; ++q) {
        mem[q] = (sp[q] ? 0.0 : m[q]) - n[q];
        xs[q] += sp[q] ? 1.f : 0.f;
      }
      continue;
    }

    // >=2 spikers: full verified random-tiebreak path
    float pos[4];
    float lmax = 0.f;
    #pragma unroll
    for (int q = 0; q < 4; ++q) {
      float r = 0.f;
      if (__any(sp[q])) {              // wave-uniform skip of threefry
        uint32_t o0, o1;
        threefry2x32(K.a[t], K.b[t], 0u, ebase + (uint32_t)(q * 4096), &o0, &o1);
        uint32_t ub = ((o0 ^ o1) >> 9) | 0x3f800000u;
        r = __uint_as_float(ub) - 1.0f;
      }
      pos[q] = sp[q] ? r : 0.f;
      lmax = fmaxf(lmax, pos[q]);
    }
    float pmax = lmax;
    #pragma unroll
    for (int o = 32; o > 0; o >>= 1) pmax = fmaxf(pmax, __shfl_xor(pmax, o));

    #pragma unroll
    for (int q = 0; q < 4; ++q) {
      float s2 = (sp[q] && pos[q] >= pmax) ? 1.f : 0.f;
      mem[q] = (sp[q] ? 0.0 : m[q]) - n[q];   // tot>=2 => some spike fired => smax=1
      xs[q] += s2;
    }
  }

  const size_t ob = ((size_t)b * 256 + c0) * 4096 + hw;
  #pragma unroll
  for (int q = 0; q < 4; ++q)
    out[ob + (size_t)q * 4096] = xs[q];
}

extern "C" void kernel_launch(void* const* d_in, const int* in_sizes, int n_in,
                              void* d_out, int out_size, void* d_ws, size_t ws_size,
                              hipStream_t stream)
{
  const float* x = (const float*)d_in[0];
  const float* W = (const float*)d_in[1];

  if (ws_size < WS_NEED) return;

  char* ws = (char*)d_ws;
  unsigned long long* nmax = (unsigned long long*)(ws + NMAX_OFF);
  int*                cs   = (int*)(ws + CS_OFF);
  double*             nbuf = (double*)(ws + NBUF_OFF);
  double*             yd   = (double*)(ws + YD_OFF);
  signed char*        xd   = (signed char*)(ws + XD_OFF);
  signed char*        wdp  = (signed char*)(ws + WD_OFF);

  float* out = (float*)d_out;

  xdigit_kernel<<<dim3(68, 4, 16), 256, 0, stream>>>(x, xd, nmax, cs);
  wdigit_kernel<<<dim3(4, 25), 256, 0, stream>>>(W, wdp, cs);
  ozconv_kernel<<<2048, 256, 0, stream>>>(xd, wdp, cs, yd, nmax);
  n_kernel<<<1, 256, 0, stream>>>(nmax, nbuf);

  Keys K;
  for (int t = 0; t < 8; ++t) {
    uint32_t a, b;
    threefry2x32(0u, 42u, 0u, (uint32_t)t, &a, &b);
    K.a[t] = a; K.b[t] = b;
  }
  double tau = exp(-0.01);

  dyn_kernel<<<NB * NH * NWD / 4, 256, 0, stream>>>(yd, nbuf, out, K, tau);
}

// Round 17
// 614.509 us; speedup vs baseline: 1.0577x; 1.0577x over previous
//
#include <hip/hip_runtime.h>
#include <stdint.h>
#include <math.h>

// Problem dims (fixed by setup_inputs)
#define NB  16
#define NCI 128
#define NCO 256
#define NH  64
#define NWD 64

#define Y_ELEMS  (NB*NCO*NH*NWD)     // 16,777,216

// ---- workspace layout (proven ws_size >= 199,299,072) ----
#define NMAX_OFF 0                               // 256 co x 8 buckets x u64 = 16384
#define CS_OFF   16384                           // 4 x 256 x i32 = 4096
#define NBUF_OFF 23552                           // 256 x f64 = 2048
#define YD_OFF   32768                           // f64 y, (b,h,w,c) layout
#define YD_BYTES ((size_t)Y_ELEMS*8)             // 134,217,728
#define XD_OFF   (YD_OFF + YD_BYTES)             // 134,250,496
#define XD_STRIDE 7168                           // 3 digits x 2304 = 6912, padded
#define XD_BYTES ((size_t)16*4*68*XD_STRIDE)     // 31,195,136
#define WD_OFF   (XD_OFF + XD_BYTES)             // 165,445,632
#define WD_BYTES ((size_t)4*4*25*8192)           // 3,276,800 (planes p=j-1, j=1..4)
#define WS_NEED  (WD_OFF + WD_BYTES)             // 168,722,432

struct Keys { uint32_t a[8]; uint32_t b[8]; };

typedef int v4i  __attribute__((ext_vector_type(4)));
typedef int v16i __attribute__((ext_vector_type(16)));

typedef __attribute__((address_space(1))) const void* gas_t;
typedef __attribute__((address_space(3))) void*       las_t;

// JAX threefry2x32 (20 rounds), bit-exact (verified rounds 2-16).
__host__ __device__ inline void threefry2x32(uint32_t k0, uint32_t k1,
                                             uint32_t x0, uint32_t x1,
                                             uint32_t* o0, uint32_t* o1)
{
  uint32_t ks2 = k0 ^ k1 ^ 0x1BD11BDAu;
  x0 += k0; x1 += k1;
#define TF_R(r) { x0 += x1; x1 = (x1 << (r)) | (x1 >> (32 - (r))); x1 ^= x0; }
  TF_R(13) TF_R(15) TF_R(26) TF_R(6)
  x0 += k1;  x1 += ks2 + 1u;
  TF_R(17) TF_R(29) TF_R(16) TF_R(24)
  x0 += ks2; x1 += k0 + 2u;
  TF_R(13) TF_R(15) TF_R(26) TF_R(6)
  x0 += k0;  x1 += k1 + 3u;
  TF_R(17) TF_R(29) TF_R(16) TF_R(24)
  x0 += k1;  x1 += ks2 + 4u;
  TF_R(13) TF_R(15) TF_R(26) TF_R(6)
  x0 += ks2; x1 += k0 + 5u;
#undef TF_R
  *o0 = x0; *o1 = x1;
}

__device__ inline unsigned long long dkey(double d)
{
  unsigned long long b = (unsigned long long)__double_as_longlong(d);
  return (b & 0x8000000000000000ULL) ? ~b : (b | 0x8000000000000000ULL);
}

// ---------------- digit extraction for x: 3 x 8-bit digits MINUS 128 (signed-safe) ----
// x = m*2^-23 -> X = x*2^40 has zero low 16 bits; digits = bytes 2..4 of X.
// xd block (b,g,row): 6912 B = [dig 3][col 72][ci-local 32], stride 7168
// Block (0,0,0) also zero-inits nmax + cs (stream order: before wdigit's atomics).
__global__ __launch_bounds__(256) void xdigit_kernel(const float* __restrict__ x,
                                                     signed char* __restrict__ xd,
                                                     unsigned long long* __restrict__ nmax,
                                                     int* __restrict__ cs)
{
  __shared__ __align__(16) signed char l[6912];
  const int row = blockIdx.x;  // padded row 0..67
  const int g   = blockIdx.y;  // ci group 0..3
  const int b   = blockIdx.z;

  if (row == 0 && g == 0 && b == 0) {
    #pragma unroll
    for (int i = 0; i < 8; ++i) nmax[i * 256 + threadIdx.x] = 0ull;
    #pragma unroll
    for (int p = 0; p < 4; ++p) cs[p * 256 + threadIdx.x] = 0;
  }

  for (int o = threadIdx.x; o < 2304; o += 256) {
    int cl = o / 72, col = o - (o / 72) * 72;
    int r = row - 2, cc = col - 2;
    float v = 0.f;
    if ((unsigned)r < 64u && (unsigned)cc < 64u)
      v = x[(((size_t)b * 128 + g * 32 + cl) * 64 + r) * 64 + cc];
    unsigned long long X = (unsigned long long)((double)v * 1099511627776.0); // 2^40 exact
    const int p = col * 32 + cl;
    l[p]        = (signed char)((int)((X >> 16) & 255u) - 128);
    l[2304 + p] = (signed char)((int)((X >> 24) & 255u) - 128);
    l[4608 + p] = (signed char)((int)((X >> 32) & 255u) - 128);
  }
  __syncthreads();
  uint4* dst = (uint4*)(xd + ((size_t)(b * 4 + g) * 68 + row) * XD_STRIDE);
  const uint4* src = (const uint4*)l;
  for (int o = threadIdx.x; o < 432; o += 256) dst[o] = src[o];
}

// ---------------- balanced 8-bit digit extraction for w: scale 2^36, store j=1..4 ----
// wd layout: [p 4][g 4][tap 25][co 256][ci-local 32] i8, plane p = j-1.
// cs[p][co] = column sums of digit j=p+1 for the -128 shift correction.
__global__ __launch_bounds__(256) void wdigit_kernel(const float* __restrict__ W,
                                                     signed char* __restrict__ wd,
                                                     int* __restrict__ cs)
{
  const int g = blockIdx.x, tap = blockIdx.y, co = threadIdx.x;
  __attribute__((aligned(16))) signed char db[5][32];
  for (int c = 0; c < 32; ++c) {
    float w = W[((size_t)co * 128 + g * 32 + c) * 25 + tap];
    long long q = __double2ll_rn((double)w * 68719476736.0); // 2^36
    #pragma unroll
    for (int j = 0; j < 5; ++j) {
      int d = (int)(q & 255);
      if (d >= 128) d -= 256;
      q = (q - d) >> 8;
      db[j][c] = (signed char)d;
    }
  }
  #pragma unroll
  for (int p = 0; p < 4; ++p) {
    const int j = p + 1;
    size_t off = (((size_t)p * 4 + g) * 25 + tap) * 8192 + (size_t)co * 32;
    *(uint4*)(wd + off)      = *(const uint4*)(&db[j][0]);
    *(uint4*)(wd + off + 16) = *(const uint4*)(&db[j][16]);
    int s = 0;
    #pragma unroll
    for (int c = 0; c < 32; ++c) s += (int)db[j][c];
    atomicAdd(&cs[p * 256 + co], s);
  }
}

// ---------------- i8-MFMA conv -> yd f64 (b,h,w,c), fused per-co max + shift-corr ----
// r11-exact structure (best of 8 schedule variants: 477us, 56 VGPR, 3+ waves/SIMD):
// shared 2x7168 LDS double-buffer, coop 7-chunk DMA staging, unroll-1 kw, no prefetch.
// 9 MFMA/tap (digit pairs i+j>=3, planes p=j-1), acc[4] = 64 AGPR.
// Epilogue computes C(co) = 128*sum_p cs[p][co]*K(p) inline.
__global__ __launch_bounds__(256, 4) void ozconv_kernel(const signed char* __restrict__ xd,
                                                        const signed char* __restrict__ wd,
                                                        const int* __restrict__ cs,
                                                        double* __restrict__ yd,
                                                        unsigned long long* __restrict__ nmax)
{
  __shared__ __align__(16) signed char A[2 * XD_STRIDE];

  const int sid = (blockIdx.x & 7) * 512 + (blockIdx.x >> 3);
  const int cog = sid >> 10;
  const int b   = (sid >> 6) & 15;
  const int h0  = sid & 63;

  const int tid  = threadIdx.x;
  const int lane = tid & 63, wv = tid >> 6;
  const int wm = wv & 1, wn = wv >> 1;
  const int l31 = lane & 31, kg = lane >> 5;
  const int co0 = cog * 64;
  const int b4  = b * 4;
  const int colbase = 32 * wm + l31;

  v16i acc[4] = {};

  auto stage = [&](int t, int bs) {
    int g = t / 5, kh = t - 5 * (t / 5);
    const signed char* src = xd + ((size_t)(b4 + g) * 68 + (h0 + kh)) * XD_STRIDE + lane * 16;
    signed char* dst = &A[bs * XD_STRIDE];
    for (int c = wv; c < 7; c += 4)
      __builtin_amdgcn_global_load_lds((gas_t)(const void*)(src + c * 1024),
                                       (las_t)(void*)(dst + c * 1024), 16, 0, 0);
  };

  stage(0, 0);
  asm volatile("s_waitcnt vmcnt(0)" ::: "memory");
  __syncthreads();

  const size_t coff = (size_t)(co0 + 32 * wn + l31) * 32 + 16 * kg;

  #pragma unroll 1
  for (int t = 0; t < 20; ++t) {
    if (t < 19) stage(t + 1, (t + 1) & 1);   // DMA next row under this row's compute

    const int g = t / 5, kh = t - 5 * (t / 5);
    const signed char* Ab = &A[(t & 1) * XD_STRIDE];
    const signed char* wbase = wd + ((size_t)(g * 25 + kh * 5)) * 8192 + coff;

    #pragma unroll 1
    for (int kw = 0; kw < 5; ++kw) {
      const int aoff = (colbase + kw) * 32 + kg * 16;
      v4i a[3];
      #pragma unroll
      for (int i = 0; i < 3; ++i)
        a[i] = *(const v4i*)(Ab + i * 2304 + aoff);
      v4i bf[4];
      #pragma unroll
      for (int p = 0; p < 4; ++p)
        bf[p] = *(const v4i*)(wbase + (size_t)p * 819200 + kw * 8192);

      // pairs with i+p>=2 (i.e. i+j>=3): 9 MFMA into acc[i+p-2]
      #pragma unroll
      for (int q = 0; q < 4; ++q) {
        const int p = 3 - q;
        #pragma unroll
        for (int i = 0; i < 3; ++i) {
          const int ss = i + p - 2;
          if (ss >= 0)
            acc[ss] = __builtin_amdgcn_mfma_i32_32x32x32_i8(a[i], bf[p], acc[ss], 0, 0, 0);
        }
      }
    }

    asm volatile("s_waitcnt vmcnt(0)" ::: "memory");
    __syncthreads();
  }

  // recombine: y = C(co) + sum_s acc_s * 2^(8s-36); store (b,h,w,c); fused per-co max
  // C(co) = 128 * sum_p cs[p][co]*K(p), K(p) = sum over kept i (i+p>=2) of 2^(8(i+p)-52)
  const double S[4] = {0x1.0p-36, 0x1.0p-28, 0x1.0p-20, 0x1.0p-12};
  const int co = co0 + 32 * wn + l31;
  const double K0 = 0x1.0p-36;
  const double K1 = 0x1.0p-36 + 0x1.0p-28;
  const double K2 = 0x1.0p-36 + 0x1.0p-28 + 0x1.0p-20;
  const double K3 = 0x1.0p-28 + 0x1.0p-20 + 0x1.0p-12;
  const double C = 128.0 * ((double)cs[co]        * K0 +
                            (double)cs[256 + co]  * K1 +
                            (double)cs[512 + co]  * K2 +
                            (double)cs[768 + co]  * K3);
  const size_t base = (((size_t)b * 64 + h0) * 64) * 256 + co;
  double lmax = -1.0e300;
  #pragma unroll
  for (int r = 0; r < 16; ++r) {
    int row = (r & 3) + 8 * (r >> 2) + 4 * kg;   // verified D-fragment row
    int w   = 32 * wm + row;
    double y = C;
    #pragma unroll
    for (int s = 0; s < 4; ++s) y = fma((double)acc[s][r], S[s], y);
    yd[base + (size_t)w * 256] = y;
    lmax = fmax(lmax, y);
  }
  lmax = fmax(lmax, __shfl_xor(lmax, 32));       // kg pair shares co
  if (kg == 0)
    atomicMax(&nmax[co * 8 + (blockIdx.x & 7)], dkey(lmax));
}

// ---------------- n[c] = max + 1e-4 ----------------
__global__ void n_kernel(const unsigned long long* __restrict__ nmax,
                         double* __restrict__ nbuf)
{
  int c = threadIdx.x;
  unsigned long long u = 0ull;
  #pragma unroll
  for (int i = 0; i < 8; ++i) {
    unsigned long long v = nmax[c * 8 + i];
    u = v > u ? v : u;
  }
  unsigned long long bits = (u & 0x8000000000000000ULL) ? (u ^ 0x8000000000000000ULL) : ~u;
  double m = __longlong_as_double((long long)bits);
  nbuf[c] = m + 1e-4;
}

// ---------------- fused squash + dynamics: 1 wave = 1 pixel (verified rounds 5-16) ----
// Wave-uniform spiker-count shortcut. 0 spikers -> pure decay; 1 spiker -> WTA winner
// is forced regardless of r -> skip ALL threefry. >=2 -> full verified path.
__global__ __launch_bounds__(256) void dyn_kernel(const double* __restrict__ yd,
                                                  const double* __restrict__ nbuf,
                                                  float* __restrict__ out,
                                                  Keys K, double tau)
{
  const int tid  = threadIdx.x;
  const int lane = tid & 63;
  const int wv   = tid >> 6;
  const int pix  = blockIdx.x * 4 + wv;    // b*4096 + hw
  const int b    = pix >> 12;
  const int hw   = pix & 4095;
  const int c0   = lane * 4;

  double y[4], n[4];
  {
    const double* yp = yd + (size_t)pix * 256 + c0;
    #pragma unroll
    for (int q = 0; q < 4; ++q) {
      n[q] = nbuf[c0 + q];
      double yraw = yp[q];
      double yc = yraw > 0.0 ? yraw : 0.0;
      y[q] = n[q] / (1.0 + exp(-((yc - 0.4 * n[q]) * (8.0 / n[q]))));
    }
  }

  double mem[4]; float xs[4];
  #pragma unroll
  for (int q = 0; q < 4; ++q) { mem[q] = y[q]; xs[q] = 0.f; }  // exact t=0 step

  const uint32_t ebase = (uint32_t)((b * 256 + c0) * 4096 + hw);

  #pragma unroll 1
  for (int t = 1; t < 8; ++t) {
    double m[4]; bool sp[4];
    int tot = 0;
    #pragma unroll
    for (int q = 0; q < 4; ++q) {
      m[q]  = mem[q] * tau + y[q];
      sp[q] = (m[q] - n[q]) > 0.0;
      tot  += __popcll(__ballot(sp[q]));
    }

    if (tot == 0) {
      #pragma unroll
      for (int q = 0; q < 4; ++q) mem[q] = m[q];
      continue;
    }
    if (tot == 1) {
      // lone spiker wins WTA unconditionally; inhibition fires (smax=1)
      #pragma unroll
      for (int q = 0; q < 4; ++q) {
        mem[q] = (sp[q] ? 0.0 : m[q]) - n[q];
        xs[q] += sp[q] ? 1.f : 0.f;
      }
      continue;
    }

    // >=2 spikers: full verified random-tiebreak path
    float pos[4];
    float lmax = 0.f;
    #pragma unroll
    for (int q = 0; q < 4; ++q) {
      float r = 0.f;
      if (__any(sp[q])) {              // wave-uniform skip of threefry
        uint32_t o0, o1;
        threefry2x32(K.a[t], K.b[t], 0u, ebase + (uint32_t)(q * 4096), &o0, &o1);
        uint32_t ub = ((o0 ^ o1) >> 9) | 0x3f800000u;
        r = __uint_as_float(ub) - 1.0f;
      }
      pos[q] = sp[q] ? r : 0.f;
      lmax = fmaxf(lmax, pos[q]);
    }
    float pmax = lmax;
    #pragma unroll
    for (int o = 32; o > 0; o >>= 1) pmax = fmaxf(pmax, __shfl_xor(pmax, o));

    #pragma unroll
    for (int q = 0; q < 4; ++q) {
      float s2 = (sp[q] && pos[q] >= pmax) ? 1.f : 0.f;
      mem[q] = (sp[q] ? 0.0 : m[q]) - n[q];   // tot>=2 => some spike fired => smax=1
      xs[q] += s2;
    }
  }

  const size_t ob = ((size_t)b * 256 + c0) * 4096 + hw;
  #pragma unroll
  for (int q = 0; q < 4; ++q)
    out[ob + (size_t)q * 4096] = xs[q];
}

extern "C" void kernel_launch(void* const* d_in, const int* in_sizes, int n_in,
                              void* d_out, int out_size, void* d_ws, size_t ws_size,
                              hipStream_t stream)
{
  const float* x = (const float*)d_in[0];
  const float* W = (const float*)d_in[1];

  if (ws_size < WS_NEED) return;

  char* ws = (char*)d_ws;
  unsigned long long* nmax = (unsigned long long*)(ws + NMAX_OFF);
  int*                cs   = (int*)(ws + CS_OFF);
  double*             nbuf = (double*)(ws + NBUF_OFF);
  double*             yd   = (double*)(ws + YD_OFF);
  signed char*        xd   = (signed char*)(ws + XD_OFF);
  signed char*        wdp  = (signed char*)(ws + WD_OFF);

  float* out = (float*)d_out;

  xdigit_kernel<<<dim3(68, 4, 16), 256, 0, stream>>>(x, xd, nmax, cs);
  wdigit_kernel<<<dim3(4, 25), 256, 0, stream>>>(W, wdp, cs);
  ozconv_kernel<<<4096, 256, 0, stream>>>(xd, wdp, cs, yd, nmax);
  n_kernel<<<1, 256, 0, stream>>>(nmax, nbuf);

  Keys K;
  for (int t = 0; t < 8; ++t) {
    uint32_t a, b;
    threefry2x32(0u, 42u, 0u, (uint32_t)t, &a, &b);
    K.a[t] = a; K.b[t] = b;
  }
  double tau = exp(-0.01);

  dyn_kernel<<<NB * NH * NWD / 4, 256, 0, stream>>>(yd, nbuf, out, K, tau);
}